// Round 1
// baseline (164.248 us; speedup 1.0000x reference)
//
#include <hip/hip_runtime.h>
#include <hip/hip_bf16.h>

#define NN 65536   // N*N rows
#define DD 128
#define NH 4
#define HDIM 32

typedef __bf16 bf16_t;
typedef __bf16 bf16x8 __attribute__((ext_vector_type(8)));
typedef __bf16 bf16x2 __attribute__((ext_vector_type(2)));
typedef float f32x4 __attribute__((ext_vector_type(4)));

// ---------------- weight transpose + bf16 cast: Wt[m][out][in] ----------------
__global__ __launch_bounds__(128) void convw_kernel(const float* __restrict__ w0,
                                                    const float* __restrict__ w1,
                                                    const float* __restrict__ w2,
                                                    const float* __restrict__ w3,
                                                    const float* __restrict__ w4,
                                                    bf16_t* __restrict__ wt) {
    int m = blockIdx.x >> 7;
    int o = blockIdx.x & 127;
    int d = threadIdx.x;
    const float* W = (m == 0) ? w0 : (m == 1) ? w1 : (m == 2) ? w2 : (m == 3) ? w3 : w4;
    wt[(m * 128 + o) * 128 + d] = (bf16_t)W[d * 128 + o];
}

// ---------------- LayerNorm: x fp32 -> z bf16 ----------------
__global__ __launch_bounds__(256) void ln_kernel(const float* __restrict__ x,
                                                 const float* __restrict__ lw,
                                                 const float* __restrict__ lb,
                                                 bf16_t* __restrict__ z) {
    int wv = threadIdx.x >> 6, lane = threadIdx.x & 63;
    int row = blockIdx.x * 4 + wv;
    int d0 = lane * 2;
    float2 v = *reinterpret_cast<const float2*>(&x[row * 128 + d0]);
    float s1 = v.x + v.y;
    float s2 = v.x * v.x + v.y * v.y;
#pragma unroll
    for (int m = 1; m < 64; m <<= 1) {
        s1 += __shfl_xor(s1, m);
        s2 += __shfl_xor(s2, m);
    }
    float mu = s1 * (1.0f / 128.0f);
    float var = s2 * (1.0f / 128.0f) - mu * mu;
    float rs = rsqrtf(var + 1e-5f);
    float z0 = (v.x - mu) * rs * lw[d0] + lb[d0];
    float z1 = (v.y - mu) * rs * lw[d0 + 1] + lb[d0 + 1];
    bf16x2 pk;
    pk[0] = (bf16_t)z0;
    pk[1] = (bf16_t)z1;
    *reinterpret_cast<bf16x2*>(&z[row * 128 + d0]) = pk;
}

// ---------------- triangle bias: biasT[h][row] = z[row]·Wb[:,h] ----------------
__global__ __launch_bounds__(256) void bias_kernel(const bf16_t* __restrict__ z,
                                                   const float* __restrict__ Wb,
                                                   float* __restrict__ biasT) {
    int t = threadIdx.x;
    int row = blockIdx.x * 64 + (t >> 2);
    int h = t & 3;
    float acc = 0.f;
#pragma unroll
    for (int i = 0; i < 16; i++) {
        bf16x8 zz = *reinterpret_cast<const bf16x8*>(&z[row * 128 + i * 8]);
#pragma unroll
        for (int j = 0; j < 8; j++) acc += (float)zz[j] * Wb[(i * 8 + j) * 4 + h];
    }
    biasT[h * NN + row] = acc;
}

// ---------------- fused QKVG projection GEMM (bf16 MFMA) ----------------
// grid (1024, 8): rb = 64-row block, nb: mat = nb>>1 (Wq,Wk,Wv,Wg), col half = (nb&1)*64
__global__ __launch_bounds__(256) void proj_kernel(const bf16_t* __restrict__ z,
                                                   const bf16_t* __restrict__ wt,
                                                   bf16_t* __restrict__ outbase) {
    __shared__ bf16_t As[64][136];
    __shared__ bf16_t Bs[64][136];
    int t = threadIdx.x;
    int rb = blockIdx.x, nb = blockIdx.y;
    int mat = nb >> 1, nc0 = (nb & 1) * 64;
    const bf16_t* wm = wt + mat * 16384;
#pragma unroll
    for (int i = 0; i < 4; i++) {
        int c = i * 256 + t;
        int r = c >> 4, off = (c & 15) * 8;
        *reinterpret_cast<bf16x8*>(&As[r][off]) =
            *reinterpret_cast<const bf16x8*>(&z[(rb * 64 + r) * 128 + off]);
        *reinterpret_cast<bf16x8*>(&Bs[r][off]) =
            *reinterpret_cast<const bf16x8*>(&wm[(nc0 + r) * 128 + off]);
    }
    __syncthreads();
    int w = t >> 6, lane = t & 63;
    int lx = lane & 15, ly = lane >> 4;
    int m0 = (w >> 1) * 32, n0 = (w & 1) * 32;
    f32x4 acc[2][2];
#pragma unroll
    for (int mt = 0; mt < 2; mt++)
#pragma unroll
        for (int nt = 0; nt < 2; nt++) acc[mt][nt] = (f32x4){0.f, 0.f, 0.f, 0.f};
#pragma unroll
    for (int ks = 0; ks < 4; ks++) {
        bf16x8 a[2], b[2];
#pragma unroll
        for (int mt = 0; mt < 2; mt++)
            a[mt] = *reinterpret_cast<bf16x8*>(&As[m0 + mt * 16 + lx][ks * 32 + ly * 8]);
#pragma unroll
        for (int nt = 0; nt < 2; nt++)
            b[nt] = *reinterpret_cast<bf16x8*>(&Bs[n0 + nt * 16 + lx][ks * 32 + ly * 8]);
#pragma unroll
        for (int mt = 0; mt < 2; mt++)
#pragma unroll
            for (int nt = 0; nt < 2; nt++)
                acc[mt][nt] = __builtin_amdgcn_mfma_f32_16x16x32_bf16(a[mt], b[nt], acc[mt][nt], 0, 0, 0);
    }
    bf16_t* dst = outbase + (size_t)mat * (NN * 128);
#pragma unroll
    for (int mt = 0; mt < 2; mt++)
#pragma unroll
        for (int nt = 0; nt < 2; nt++)
#pragma unroll
            for (int r = 0; r < 4; r++) {
                int row = rb * 64 + m0 + mt * 16 + ly * 4 + r;
                int col = nc0 + n0 + nt * 16 + lx;
                float v = acc[mt][nt][r];
                if (mat == 3) v = 1.0f / (1.0f + __expf(-v));  // fused sigmoid for G
                dst[row * 128 + col] = (bf16_t)v;
            }
}

// ---------------- flash attention per (b,h) ----------------
__global__ __launch_bounds__(256) void attn_kernel(const bf16_t* __restrict__ qm,
                                                   const bf16_t* __restrict__ km,
                                                   const bf16_t* __restrict__ vm,
                                                   const float* __restrict__ biasT,
                                                   bf16_t* __restrict__ om) {
    __shared__ bf16_t Kl[256][40];
    __shared__ bf16_t Vt[32][264];
    __shared__ bf16_t Pl[4][64][40];
    int t = threadIdx.x;
    int b = blockIdx.x >> 2, h = blockIdx.x & 3;
    // stage K: Kl[key][c] (padded rows)
#pragma unroll
    for (int i = 0; i < 4; i++) {
        int c = i * 256 + t;
        int key = c >> 2, part = c & 3;
        *reinterpret_cast<bf16x8*>(&Kl[key][part * 8]) =
            *reinterpret_cast<const bf16x8*>(&km[(b * 256 + key) * 128 + h * 32 + part * 8]);
    }
    // stage V transposed: Vt[c][key]
    {
        int key = t;
        bf16x8 vv[4];
#pragma unroll
        for (int j = 0; j < 4; j++)
            vv[j] = *reinterpret_cast<const bf16x8*>(&vm[(b * 256 + key) * 128 + h * 32 + j * 8]);
#pragma unroll
        for (int j = 0; j < 4; j++)
#pragma unroll
            for (int e = 0; e < 8; e++) Vt[j * 8 + e][key] = vv[j][e];
    }
    __syncthreads();

    int w = t >> 6, lane = t & 63;
    int lx = lane & 15, ly = lane >> 4;
    int q0 = w * 64;
    const float scale = 0.17677669529663687f;  // 1/sqrt(32)

    bf16x8 qa[4];
#pragma unroll
    for (int qt = 0; qt < 4; qt++)
        qa[qt] = *reinterpret_cast<const bf16x8*>(
            &qm[(b * 256 + q0 + qt * 16 + lx) * 128 + h * 32 + ly * 8]);

    float mrow[4][4], lsum[4][4];
    f32x4 of[4][2];
#pragma unroll
    for (int qt = 0; qt < 4; qt++) {
#pragma unroll
        for (int r = 0; r < 4; r++) { mrow[qt][r] = -1e30f; lsum[qt][r] = 0.f; }
#pragma unroll
        for (int ct = 0; ct < 2; ct++) of[qt][ct] = (f32x4){0.f, 0.f, 0.f, 0.f};
    }

    for (int kc = 0; kc < 8; kc++) {
        bf16x8 kb[2];
#pragma unroll
        for (int kt = 0; kt < 2; kt++)
            kb[kt] = *reinterpret_cast<bf16x8*>(&Kl[kc * 32 + kt * 16 + lx][ly * 8]);
        f32x4 s[4][2];
        f32x4 zf = (f32x4){0.f, 0.f, 0.f, 0.f};
#pragma unroll
        for (int qt = 0; qt < 4; qt++)
#pragma unroll
            for (int kt = 0; kt < 2; kt++)
                s[qt][kt] = __builtin_amdgcn_mfma_f32_16x16x32_bf16(qa[qt], kb[kt], zf, 0, 0, 0);
        // scale + bias
        float sv[4][2][4];
#pragma unroll
        for (int qt = 0; qt < 4; qt++)
#pragma unroll
            for (int kt = 0; kt < 2; kt++)
#pragma unroll
                for (int r = 0; r < 4; r++) {
                    int q = q0 + qt * 16 + ly * 4 + r;
                    int key = kc * 32 + kt * 16 + lx;
                    sv[qt][kt][r] = s[qt][kt][r] * scale + biasT[h * NN + q * 256 + key];
                }
        // online softmax (reduce over the 16 lanes of lx)
#pragma unroll
        for (int qt = 0; qt < 4; qt++) {
#pragma unroll
            for (int r = 0; r < 4; r++) {
                float mx = fmaxf(sv[qt][0][r], sv[qt][1][r]);
                mx = fmaxf(mx, __shfl_xor(mx, 1));
                mx = fmaxf(mx, __shfl_xor(mx, 2));
                mx = fmaxf(mx, __shfl_xor(mx, 4));
                mx = fmaxf(mx, __shfl_xor(mx, 8));
                float nm = fmaxf(mrow[qt][r], mx);
                float al = __expf(mrow[qt][r] - nm);
                mrow[qt][r] = nm;
                float p0 = __expf(sv[qt][0][r] - nm);
                float p1 = __expf(sv[qt][1][r] - nm);
                Pl[w][qt * 16 + ly * 4 + r][lx] = (bf16_t)p0;
                Pl[w][qt * 16 + ly * 4 + r][16 + lx] = (bf16_t)p1;
                float ps = p0 + p1;
                ps += __shfl_xor(ps, 1);
                ps += __shfl_xor(ps, 2);
                ps += __shfl_xor(ps, 4);
                ps += __shfl_xor(ps, 8);
                lsum[qt][r] = lsum[qt][r] * al + ps;
                of[qt][0][r] *= al;
                of[qt][1][r] *= al;
            }
        }
        // PV
        bf16x8 vb[2], pa[4];
#pragma unroll
        for (int ct = 0; ct < 2; ct++)
            vb[ct] = *reinterpret_cast<bf16x8*>(&Vt[ct * 16 + lx][kc * 32 + ly * 8]);
#pragma unroll
        for (int qt = 0; qt < 4; qt++)
            pa[qt] = *reinterpret_cast<bf16x8*>(&Pl[w][qt * 16 + lx][ly * 8]);
#pragma unroll
        for (int qt = 0; qt < 4; qt++)
#pragma unroll
            for (int ct = 0; ct < 2; ct++)
                of[qt][ct] = __builtin_amdgcn_mfma_f32_16x16x32_bf16(pa[qt], vb[ct], of[qt][ct], 0, 0, 0);
    }
    // epilogue: normalize and store o (bf16)
#pragma unroll
    for (int qt = 0; qt < 4; qt++)
#pragma unroll
        for (int r = 0; r < 4; r++) {
            float inv = 1.0f / lsum[qt][r];
            int row = b * 256 + q0 + qt * 16 + ly * 4 + r;
#pragma unroll
            for (int ct = 0; ct < 2; ct++)
                om[row * 128 + h * 32 + ct * 16 + lx] = (bf16_t)(of[qt][ct][r] * inv);
        }
}

// ---------------- final: out = (o*g) @ Wo, fp32 out ----------------
__global__ __launch_bounds__(256) void final_kernel(const bf16_t* __restrict__ om,
                                                    const bf16_t* __restrict__ gm,
                                                    const bf16_t* __restrict__ wot,
                                                    float* __restrict__ out) {
    __shared__ bf16_t As[64][136];
    __shared__ bf16_t Bs[64][136];
    int t = threadIdx.x;
    int rb = blockIdx.x, nc0 = blockIdx.y * 64;
#pragma unroll
    for (int i = 0; i < 4; i++) {
        int c = i * 256 + t;
        int r = c >> 4, off = (c & 15) * 8;
        bf16x8 o8 = *reinterpret_cast<const bf16x8*>(&om[(rb * 64 + r) * 128 + off]);
        bf16x8 g8 = *reinterpret_cast<const bf16x8*>(&gm[(rb * 64 + r) * 128 + off]);
        bf16x8 p8;
#pragma unroll
        for (int e = 0; e < 8; e++) p8[e] = (bf16_t)((float)o8[e] * (float)g8[e]);
        *reinterpret_cast<bf16x8*>(&As[r][off]) = p8;
        *reinterpret_cast<bf16x8*>(&Bs[r][off]) =
            *reinterpret_cast<const bf16x8*>(&wot[(nc0 + r) * 128 + off]);
    }
    __syncthreads();
    int w = t >> 6, lane = t & 63;
    int lx = lane & 15, ly = lane >> 4;
    int m0 = (w >> 1) * 32, n0 = (w & 1) * 32;
    f32x4 acc[2][2];
#pragma unroll
    for (int mt = 0; mt < 2; mt++)
#pragma unroll
        for (int nt = 0; nt < 2; nt++) acc[mt][nt] = (f32x4){0.f, 0.f, 0.f, 0.f};
#pragma unroll
    for (int ks = 0; ks < 4; ks++) {
        bf16x8 a[2], bb[2];
#pragma unroll
        for (int mt = 0; mt < 2; mt++)
            a[mt] = *reinterpret_cast<bf16x8*>(&As[m0 + mt * 16 + lx][ks * 32 + ly * 8]);
#pragma unroll
        for (int nt = 0; nt < 2; nt++)
            bb[nt] = *reinterpret_cast<bf16x8*>(&Bs[n0 + nt * 16 + lx][ks * 32 + ly * 8]);
#pragma unroll
        for (int mt = 0; mt < 2; mt++)
#pragma unroll
            for (int nt = 0; nt < 2; nt++)
                acc[mt][nt] = __builtin_amdgcn_mfma_f32_16x16x32_bf16(a[mt], bb[nt], acc[mt][nt], 0, 0, 0);
    }
#pragma unroll
    for (int mt = 0; mt < 2; mt++)
#pragma unroll
        for (int nt = 0; nt < 2; nt++)
#pragma unroll
            for (int r = 0; r < 4; r++) {
                int row = rb * 64 + m0 + mt * 16 + ly * 4 + r;
                int col = nc0 + n0 + nt * 16 + lx;
                out[row * 128 + col] = acc[mt][nt][r];
            }
}

extern "C" void kernel_launch(void* const* d_in, const int* in_sizes, int n_in,
                              void* d_out, int out_size, void* d_ws, size_t ws_size,
                              hipStream_t stream) {
    const float* x   = (const float*)d_in[0];
    const float* lnw = (const float*)d_in[1];
    const float* lnb = (const float*)d_in[2];
    const float* Wb  = (const float*)d_in[3];
    const float* Wq  = (const float*)d_in[4];
    const float* Wk  = (const float*)d_in[5];
    const float* Wv  = (const float*)d_in[6];
    const float* Wg  = (const float*)d_in[7];
    const float* Wo  = (const float*)d_in[8];
    float* out = (float*)d_out;

    char* ws = (char*)d_ws;
    const size_t MAT = (size_t)NN * 128 * sizeof(bf16_t);  // 16 MB
    bf16_t* z     = (bf16_t*)(ws);
    bf16_t* qkvg  = (bf16_t*)(ws + MAT);          // q,k,v,g contiguous
    bf16_t* omat  = (bf16_t*)(ws + 5 * MAT);
    bf16_t* wt    = (bf16_t*)(ws + 6 * MAT);      // 5 * 128*128 bf16
    float*  biasT = (float*)(ws + 6 * MAT + 163840);

    bf16_t* q = qkvg;
    bf16_t* k = qkvg + (size_t)NN * 128;
    bf16_t* v = qkvg + 2 * (size_t)NN * 128;
    bf16_t* g = qkvg + 3 * (size_t)NN * 128;

    convw_kernel<<<640, 128, 0, stream>>>(Wq, Wk, Wv, Wg, Wo, wt);
    ln_kernel<<<16384, 256, 0, stream>>>(x, lnw, lnb, z);
    bias_kernel<<<1024, 256, 0, stream>>>(z, Wb, biasT);
    proj_kernel<<<dim3(1024, 8), 256, 0, stream>>>(z, wt, qkvg);
    attn_kernel<<<1024, 256, 0, stream>>>(q, k, v, biasT, omat);
    final_kernel<<<dim3(1024, 2), 256, 0, stream>>>(omat, g, wt + 4 * 16384, out);
}

// Round 2
// 153.706 us; speedup vs baseline: 1.0686x; 1.0686x over previous
//
#include <hip/hip_runtime.h>
#include <hip/hip_bf16.h>

#define NN 65536   // N*N rows
#define DD 128
#define NH 4
#define HDIM 32

typedef __bf16 bf16_t;
typedef __bf16 bf16x8 __attribute__((ext_vector_type(8)));
typedef __bf16 bf16x2 __attribute__((ext_vector_type(2)));
typedef float f32x4 __attribute__((ext_vector_type(4)));
typedef float f32x16 __attribute__((ext_vector_type(16)));
typedef unsigned int u32;
typedef unsigned int u32x4 __attribute__((ext_vector_type(4)));

__device__ inline u32 pk2(float a, float b) {
    bf16x2 t;
    t[0] = (bf16_t)a;
    t[1] = (bf16_t)b;
    return __builtin_bit_cast(u32, t);
}
__device__ inline bf16x8 frag4(u32 a, u32 b, u32 c, u32 d) {
    u32x4 t = {a, b, c, d};
    return __builtin_bit_cast(bf16x8, t);
}

// ---------------- weight transpose + bf16 cast: Wt[m][out][in] ----------------
__global__ __launch_bounds__(128) void convw_kernel(const float* __restrict__ w0,
                                                    const float* __restrict__ w1,
                                                    const float* __restrict__ w2,
                                                    const float* __restrict__ w3,
                                                    const float* __restrict__ w4,
                                                    bf16_t* __restrict__ wt) {
    int m = blockIdx.x >> 7;
    int o = blockIdx.x & 127;
    int d = threadIdx.x;
    const float* W = (m == 0) ? w0 : (m == 1) ? w1 : (m == 2) ? w2 : (m == 3) ? w3 : w4;
    wt[(m * 128 + o) * 128 + d] = (bf16_t)W[d * 128 + o];
}

// ---------------- LayerNorm + fused triangle bias ----------------
// biasL[h][row] = (z_row . Wb[:,h]) * log2(e)   (exp2-domain bias)
__global__ __launch_bounds__(256) void ln_kernel(const float* __restrict__ x,
                                                 const float* __restrict__ lw,
                                                 const float* __restrict__ lb,
                                                 const float* __restrict__ Wb,
                                                 bf16_t* __restrict__ z,
                                                 float* __restrict__ biasL) {
    int wv = threadIdx.x >> 6, lane = threadIdx.x & 63;
    int row = blockIdx.x * 4 + wv;
    int d0 = lane * 2;
    float2 v = *reinterpret_cast<const float2*>(&x[row * 128 + d0]);
    float s1 = v.x + v.y;
    float s2 = v.x * v.x + v.y * v.y;
#pragma unroll
    for (int m = 1; m < 64; m <<= 1) {
        s1 += __shfl_xor(s1, m);
        s2 += __shfl_xor(s2, m);
    }
    float mu = s1 * (1.0f / 128.0f);
    float var = s2 * (1.0f / 128.0f) - mu * mu;
    float rs = rsqrtf(var + 1e-5f);
    float z0 = (v.x - mu) * rs * lw[d0] + lb[d0];
    float z1 = (v.y - mu) * rs * lw[d0 + 1] + lb[d0 + 1];
    bf16x2 pk;
    pk[0] = (bf16_t)z0;
    pk[1] = (bf16_t)z1;
    *reinterpret_cast<bf16x2*>(&z[row * 128 + d0]) = pk;
    // fused bias
    f32x4 wb0 = *reinterpret_cast<const f32x4*>(&Wb[d0 * 4]);
    f32x4 wb1 = *reinterpret_cast<const f32x4*>(&Wb[d0 * 4 + 4]);
    f32x4 pb;
#pragma unroll
    for (int hh = 0; hh < 4; hh++) pb[hh] = z0 * wb0[hh] + z1 * wb1[hh];
#pragma unroll
    for (int m = 1; m < 64; m <<= 1) {
#pragma unroll
        for (int hh = 0; hh < 4; hh++) pb[hh] += __shfl_xor(pb[hh], m);
    }
    if (lane == 0) {
#pragma unroll
        for (int hh = 0; hh < 4; hh++)
            biasL[hh * NN + row] = pb[hh] * 1.4426950408889634f;
    }
}

// ---------------- fused QKVG projection GEMM (z staged once per block) ----------------
__global__ __launch_bounds__(256) void proj_kernel(const bf16_t* __restrict__ z,
                                                   const bf16_t* __restrict__ wt,
                                                   bf16_t* __restrict__ outbase) {
    __shared__ bf16_t As[64][136];
    __shared__ bf16_t Bs[64][136];
    int t = threadIdx.x;
    int rb = blockIdx.x;
#pragma unroll
    for (int i = 0; i < 4; i++) {
        int c = i * 256 + t;
        int r = c >> 4, off = (c & 15) * 8;
        *reinterpret_cast<bf16x8*>(&As[r][off]) =
            *reinterpret_cast<const bf16x8*>(&z[(rb * 64 + r) * 128 + off]);
    }
    __syncthreads();
    int w = t >> 6, lane = t & 63;
    int lx = lane & 15, ly = lane >> 4;
    int m0 = (w >> 1) * 32, n0 = (w & 1) * 32;
    bf16x8 af[2][4];
#pragma unroll
    for (int mt = 0; mt < 2; mt++)
#pragma unroll
        for (int ks = 0; ks < 4; ks++)
            af[mt][ks] = *reinterpret_cast<bf16x8*>(&As[m0 + mt * 16 + lx][ks * 32 + ly * 8]);

    for (int nb = 0; nb < 8; nb++) {
        int mat = nb >> 1, nc0 = (nb & 1) * 64;
        const bf16_t* wm = wt + mat * 16384;
#pragma unroll
        for (int i = 0; i < 4; i++) {
            int c = i * 256 + t;
            int r = c >> 4, off = (c & 15) * 8;
            *reinterpret_cast<bf16x8*>(&Bs[r][off]) =
                *reinterpret_cast<const bf16x8*>(&wm[(nc0 + r) * 128 + off]);
        }
        __syncthreads();
        f32x4 acc[2][2];
#pragma unroll
        for (int mt = 0; mt < 2; mt++)
#pragma unroll
            for (int nt = 0; nt < 2; nt++) acc[mt][nt] = (f32x4){0.f, 0.f, 0.f, 0.f};
#pragma unroll
        for (int ks = 0; ks < 4; ks++) {
            bf16x8 bfr[2];
#pragma unroll
            for (int nt = 0; nt < 2; nt++)
                bfr[nt] = *reinterpret_cast<bf16x8*>(&Bs[n0 + nt * 16 + lx][ks * 32 + ly * 8]);
#pragma unroll
            for (int mt = 0; mt < 2; mt++)
#pragma unroll
                for (int nt = 0; nt < 2; nt++)
                    acc[mt][nt] = __builtin_amdgcn_mfma_f32_16x16x32_bf16(af[mt][ks], bfr[nt], acc[mt][nt], 0, 0, 0);
        }
        bf16_t* dst = outbase + (size_t)mat * ((size_t)NN * 128);
#pragma unroll
        for (int mt = 0; mt < 2; mt++)
#pragma unroll
            for (int nt = 0; nt < 2; nt++)
#pragma unroll
                for (int r = 0; r < 4; r++) {
                    int row = rb * 64 + m0 + mt * 16 + ly * 4 + r;
                    int col = nc0 + n0 + nt * 16 + lx;
                    float v = acc[mt][nt][r];
                    if (mat == 3) v = 1.0f / (1.0f + __expf(-v));  // fused sigmoid for G
                    dst[row * 128 + col] = (bf16_t)v;
                }
        __syncthreads();
    }
}

// ---------------- attention: swapped QK^T, in-register softmax ----------------
__global__ __launch_bounds__(256, 2) void attn_kernel(const bf16_t* __restrict__ qm,
                                                      const bf16_t* __restrict__ km,
                                                      const bf16_t* __restrict__ vm,
                                                      const float* __restrict__ biasL,
                                                      bf16_t* __restrict__ om) {
    __shared__ bf16_t Kl[256][40];   // 80B rows: 5 16B-slots -> conflict-free b128
    __shared__ bf16_t Vt[32][264];   // 528B rows: 33 slots -> conflict-free b128
    int t = threadIdx.x;
    int b = blockIdx.x >> 2, h = blockIdx.x & 3;
    // stage K
#pragma unroll
    for (int i = 0; i < 4; i++) {
        int c = i * 256 + t;
        int key = c >> 2, slot = c & 3;
        *reinterpret_cast<bf16x8*>(&Kl[key][slot * 8]) =
            *reinterpret_cast<const bf16x8*>(&km[(b * 256 + key) * 128 + h * 32 + slot * 8]);
    }
    // stage V transposed
    {
        int key = t;
        bf16x8 vv[4];
#pragma unroll
        for (int j = 0; j < 4; j++)
            vv[j] = *reinterpret_cast<const bf16x8*>(&vm[(b * 256 + key) * 128 + h * 32 + j * 8]);
#pragma unroll
        for (int j = 0; j < 4; j++)
#pragma unroll
            for (int e = 0; e < 8; e++) Vt[j * 8 + e][key] = vv[j][e];
    }
    __syncthreads();

    int w = t >> 6, lane = t & 63;
    int rsel = lane & 31, hi = lane >> 5;
    int hi8 = hi * 8;
    bool lo = (hi == 0);
    const float SCL2 = 0.17677669529663687f * 1.4426950408889634f;  // scale * log2(e)

    for (int qt = 0; qt < 2; qt++) {
        int qpos = w * 64 + qt * 32 + rsel;
        const bf16_t* qrow = &qm[(size_t)(b * 256 + qpos) * 128 + h * 32];
        bf16x8 qf0 = *reinterpret_cast<const bf16x8*>(qrow + hi8);
        bf16x8 qf1 = *reinterpret_cast<const bf16x8*>(qrow + 16 + hi8);

        // QK^T (swapped): C[key_row, q_col], col = lane&31 = q
        f32x16 s[8];
#pragma unroll
        for (int kt = 0; kt < 8; kt++) {
            bf16x8 k0 = *reinterpret_cast<bf16x8*>(&Kl[kt * 32 + rsel][hi8]);
            bf16x8 k1 = *reinterpret_cast<bf16x8*>(&Kl[kt * 32 + rsel][16 + hi8]);
            f32x16 acc;
#pragma unroll
            for (int i = 0; i < 16; i++) acc[i] = 0.f;
            acc = __builtin_amdgcn_mfma_f32_32x32x16_bf16(k0, qf0, acc, 0, 0, 0);
            acc = __builtin_amdgcn_mfma_f32_32x32x16_bf16(k1, qf1, acc, 0, 0, 0);
            s[kt] = acc;
        }

        // scale+bias (exp2 domain), row max
        const float* bp = biasL + h * NN + qpos * 256;
        float mx = -1e30f;
#pragma unroll
        for (int kt = 0; kt < 8; kt++) {
#pragma unroll
            for (int g = 0; g < 4; g++) {
                f32x4 bb = *reinterpret_cast<const f32x4*>(bp + kt * 32 + g * 8 + hi * 4);
#pragma unroll
                for (int i = 0; i < 4; i++) {
                    float v = s[kt][g * 4 + i] * SCL2 + bb[i];
                    s[kt][g * 4 + i] = v;
                    mx = fmaxf(mx, v);
                }
            }
        }
        mx = fmaxf(mx, __shfl_xor(mx, 32));

        // exp2 + row sum
        float lsum = 0.f;
#pragma unroll
        for (int kt = 0; kt < 8; kt++) {
            float lt = 0.f;
#pragma unroll
            for (int r = 0; r < 16; r++) {
                float p = __builtin_amdgcn_exp2f(s[kt][r] - mx);
                s[kt][r] = p;
                lt += p;
            }
            lsum += lt;
        }
        lsum += __shfl_xor(lsum, 32);

        // build P^T B-fragments (keys contiguous per lane-half)
        bf16x8 pf[8][2];
#pragma unroll
        for (int kt = 0; kt < 8; kt++) {
            u32 wv[8];
#pragma unroll
            for (int g = 0; g < 4; g++) {
                wv[2 * g] = pk2(s[kt][4 * g], s[kt][4 * g + 1]);
                wv[2 * g + 1] = pk2(s[kt][4 * g + 2], s[kt][4 * g + 3]);
            }
            u32 p0 = __shfl_xor(wv[0], 32), p1 = __shfl_xor(wv[1], 32);
            u32 p2 = __shfl_xor(wv[2], 32), p3 = __shfl_xor(wv[3], 32);
            u32 p4 = __shfl_xor(wv[4], 32), p5 = __shfl_xor(wv[5], 32);
            u32 p6 = __shfl_xor(wv[6], 32), p7 = __shfl_xor(wv[7], 32);
            pf[kt][0] = frag4(lo ? wv[0] : p2, lo ? wv[1] : p3,
                              lo ? p0 : wv[2], lo ? p1 : wv[3]);
            pf[kt][1] = frag4(lo ? wv[4] : p6, lo ? wv[5] : p7,
                              lo ? p4 : wv[6], lo ? p5 : wv[7]);
        }

        // PV: o^T[c_row, q_col] = V^T . P
        f32x16 of;
#pragma unroll
        for (int i = 0; i < 16; i++) of[i] = 0.f;
#pragma unroll
        for (int kt = 0; kt < 8; kt++) {
            bf16x8 va = *reinterpret_cast<bf16x8*>(&Vt[rsel][kt * 32 + hi8]);
            bf16x8 vb = *reinterpret_cast<bf16x8*>(&Vt[rsel][kt * 32 + 16 + hi8]);
            of = __builtin_amdgcn_mfma_f32_32x32x16_bf16(va, pf[kt][0], of, 0, 0, 0);
            of = __builtin_amdgcn_mfma_f32_32x32x16_bf16(vb, pf[kt][1], of, 0, 0, 0);
        }

        // epilogue: normalize, pack to contiguous c per lane, store 2x16B
        float linv = 1.0f / lsum;
        u32 ow[8];
#pragma unroll
        for (int g = 0; g < 4; g++) {
            ow[2 * g] = pk2(of[4 * g] * linv, of[4 * g + 1] * linv);
            ow[2 * g + 1] = pk2(of[4 * g + 2] * linv, of[4 * g + 3] * linv);
        }
        u32 q0 = __shfl_xor(ow[0], 32), q1 = __shfl_xor(ow[1], 32);
        u32 q2 = __shfl_xor(ow[2], 32), q3 = __shfl_xor(ow[3], 32);
        u32 q4 = __shfl_xor(ow[4], 32), q5 = __shfl_xor(ow[5], 32);
        u32 q6 = __shfl_xor(ow[6], 32), q7 = __shfl_xor(ow[7], 32);
        u32x4 st0 = {lo ? ow[0] : q2, lo ? ow[1] : q3, lo ? q0 : ow[2], lo ? q1 : ow[3]};
        u32x4 st1 = {lo ? ow[4] : q6, lo ? ow[5] : q7, lo ? q4 : ow[6], lo ? q5 : ow[7]};
        bf16_t* orow = &om[(size_t)(b * 256 + qpos) * 128 + h * 32];
        *reinterpret_cast<u32x4*>(orow + hi8) = st0;
        *reinterpret_cast<u32x4*>(orow + 16 + hi8) = st1;
    }
}

// ---------------- final: out = (o*g) @ Wo, fp32 out ----------------
__global__ __launch_bounds__(256) void final_kernel(const bf16_t* __restrict__ om,
                                                    const bf16_t* __restrict__ gm,
                                                    const bf16_t* __restrict__ wot,
                                                    float* __restrict__ out) {
    __shared__ bf16_t As[64][136];
    __shared__ bf16_t Bs[64][136];
    int t = threadIdx.x;
    int rb = blockIdx.x;
#pragma unroll
    for (int i = 0; i < 4; i++) {
        int c = i * 256 + t;
        int r = c >> 4, off = (c & 15) * 8;
        bf16x8 o8 = *reinterpret_cast<const bf16x8*>(&om[(rb * 64 + r) * 128 + off]);
        bf16x8 g8 = *reinterpret_cast<const bf16x8*>(&gm[(rb * 64 + r) * 128 + off]);
        bf16x8 p8;
#pragma unroll
        for (int e = 0; e < 8; e++) p8[e] = (bf16_t)((float)o8[e] * (float)g8[e]);
        *reinterpret_cast<bf16x8*>(&As[r][off]) = p8;
    }
    __syncthreads();
    int w = t >> 6, lane = t & 63;
    int lx = lane & 15, ly = lane >> 4;
    int m0 = (w >> 1) * 32, n0 = (w & 1) * 32;
    bf16x8 af[2][4];
#pragma unroll
    for (int mt = 0; mt < 2; mt++)
#pragma unroll
        for (int ks = 0; ks < 4; ks++)
            af[mt][ks] = *reinterpret_cast<bf16x8*>(&As[m0 + mt * 16 + lx][ks * 32 + ly * 8]);

    for (int half = 0; half < 2; half++) {
        int nc0 = half * 64;
#pragma unroll
        for (int i = 0; i < 4; i++) {
            int c = i * 256 + t;
            int r = c >> 4, off = (c & 15) * 8;
            *reinterpret_cast<bf16x8*>(&Bs[r][off]) =
                *reinterpret_cast<const bf16x8*>(&wot[(nc0 + r) * 128 + off]);
        }
        __syncthreads();
        f32x4 acc[2][2];
#pragma unroll
        for (int mt = 0; mt < 2; mt++)
#pragma unroll
            for (int nt = 0; nt < 2; nt++) acc[mt][nt] = (f32x4){0.f, 0.f, 0.f, 0.f};
#pragma unroll
        for (int ks = 0; ks < 4; ks++) {
            bf16x8 bfr[2];
#pragma unroll
            for (int nt = 0; nt < 2; nt++)
                bfr[nt] = *reinterpret_cast<bf16x8*>(&Bs[n0 + nt * 16 + lx][ks * 32 + ly * 8]);
#pragma unroll
            for (int mt = 0; mt < 2; mt++)
#pragma unroll
                for (int nt = 0; nt < 2; nt++)
                    acc[mt][nt] = __builtin_amdgcn_mfma_f32_16x16x32_bf16(af[mt][ks], bfr[nt], acc[mt][nt], 0, 0, 0);
        }
#pragma unroll
        for (int mt = 0; mt < 2; mt++)
#pragma unroll
            for (int nt = 0; nt < 2; nt++)
#pragma unroll
                for (int r = 0; r < 4; r++) {
                    int row = rb * 64 + m0 + mt * 16 + ly * 4 + r;
                    int col = nc0 + n0 + nt * 16 + lx;
                    out[row * 128 + col] = acc[mt][nt][r];
                }
        __syncthreads();
    }
}

extern "C" void kernel_launch(void* const* d_in, const int* in_sizes, int n_in,
                              void* d_out, int out_size, void* d_ws, size_t ws_size,
                              hipStream_t stream) {
    const float* x   = (const float*)d_in[0];
    const float* lnw = (const float*)d_in[1];
    const float* lnb = (const float*)d_in[2];
    const float* Wb  = (const float*)d_in[3];
    const float* Wq  = (const float*)d_in[4];
    const float* Wk  = (const float*)d_in[5];
    const float* Wv  = (const float*)d_in[6];
    const float* Wg  = (const float*)d_in[7];
    const float* Wo  = (const float*)d_in[8];
    float* out = (float*)d_out;

    char* ws = (char*)d_ws;
    const size_t MAT = (size_t)NN * 128 * sizeof(bf16_t);  // 16 MB
    bf16_t* z     = (bf16_t*)(ws);
    bf16_t* qkvg  = (bf16_t*)(ws + MAT);          // q,k,v,g contiguous
    bf16_t* omat  = (bf16_t*)(ws + 5 * MAT);
    bf16_t* wt    = (bf16_t*)(ws + 6 * MAT);      // 5 * 128*128 bf16
    float*  biasL = (float*)(ws + 6 * MAT + 163840);

    bf16_t* q = qkvg;
    bf16_t* k = qkvg + (size_t)NN * 128;
    bf16_t* v = qkvg + 2 * (size_t)NN * 128;
    bf16_t* g = qkvg + 3 * (size_t)NN * 128;

    convw_kernel<<<640, 128, 0, stream>>>(Wq, Wk, Wv, Wg, Wo, wt);
    ln_kernel<<<16384, 256, 0, stream>>>(x, lnw, lnb, Wb, z, biasL);
    proj_kernel<<<1024, 256, 0, stream>>>(z, wt, qkvg);
    attn_kernel<<<1024, 256, 0, stream>>>(q, k, v, biasL, omat);
    final_kernel<<<1024, 256, 0, stream>>>(omat, g, wt + 4 * 16384, out);
}

// Round 3
// 102.559 us; speedup vs baseline: 1.6015x; 1.4987x over previous
//
#include <hip/hip_runtime.h>
#include <hip/hip_bf16.h>

#define NN 65536   // N*N rows
#define DD 128
#define NH 4
#define HDIM 32

typedef __bf16 bf16_t;
typedef __bf16 bf16x8 __attribute__((ext_vector_type(8)));
typedef __bf16 bf16x2 __attribute__((ext_vector_type(2)));
typedef float f32x4 __attribute__((ext_vector_type(4)));
typedef float f32x16 __attribute__((ext_vector_type(16)));
typedef unsigned int u32;
typedef unsigned int u32x4 __attribute__((ext_vector_type(4)));

__device__ inline u32 pk2(float a, float b) {
    bf16x2 t;
    t[0] = (bf16_t)a;
    t[1] = (bf16_t)b;
    return __builtin_bit_cast(u32, t);
}
__device__ inline bf16x8 frag4(u32 a, u32 b, u32 c, u32 d) {
    u32x4 t = {a, b, c, d};
    return __builtin_bit_cast(bf16x8, t);
}

// ---------------- weight transpose + bf16 cast: Wt[m][out][in] ----------------
__global__ __launch_bounds__(128) void convw_kernel(const float* __restrict__ w0,
                                                    const float* __restrict__ w1,
                                                    const float* __restrict__ w2,
                                                    const float* __restrict__ w3,
                                                    const float* __restrict__ w4,
                                                    bf16_t* __restrict__ wt) {
    int m = blockIdx.x >> 7;
    int o = blockIdx.x & 127;
    int d = threadIdx.x;
    const float* W = (m == 0) ? w0 : (m == 1) ? w1 : (m == 2) ? w2 : (m == 3) ? w3 : w4;
    wt[(m * 128 + o) * 128 + d] = (bf16_t)W[d * 128 + o];
}

// ---------------- LayerNorm + fused triangle bias ----------------
// bias2[h][k][q] = (z_row(q*256+k) . Wb[:,h]) * log2(e)   (exp2-domain bias)
__global__ __launch_bounds__(256) void ln_kernel(const float* __restrict__ x,
                                                 const float* __restrict__ lw,
                                                 const float* __restrict__ lb,
                                                 const float* __restrict__ Wb,
                                                 bf16_t* __restrict__ z,
                                                 float* __restrict__ bias2) {
    int wv = threadIdx.x >> 6, lane = threadIdx.x & 63;
    int row = blockIdx.x * 4 + wv;
    int d0 = lane * 2;
    float2 v = *reinterpret_cast<const float2*>(&x[row * 128 + d0]);
    float s1 = v.x + v.y;
    float s2 = v.x * v.x + v.y * v.y;
#pragma unroll
    for (int m = 1; m < 64; m <<= 1) {
        s1 += __shfl_xor(s1, m);
        s2 += __shfl_xor(s2, m);
    }
    float mu = s1 * (1.0f / 128.0f);
    float var = s2 * (1.0f / 128.0f) - mu * mu;
    float rs = rsqrtf(var + 1e-5f);
    float z0 = (v.x - mu) * rs * lw[d0] + lb[d0];
    float z1 = (v.y - mu) * rs * lw[d0 + 1] + lb[d0 + 1];
    bf16x2 pk;
    pk[0] = (bf16_t)z0;
    pk[1] = (bf16_t)z1;
    *reinterpret_cast<bf16x2*>(&z[row * 128 + d0]) = pk;
    // fused bias
    f32x4 wb0 = *reinterpret_cast<const f32x4*>(&Wb[d0 * 4]);
    f32x4 wb1 = *reinterpret_cast<const f32x4*>(&Wb[d0 * 4 + 4]);
    f32x4 pb;
#pragma unroll
    for (int hh = 0; hh < 4; hh++) pb[hh] = z0 * wb0[hh] + z1 * wb1[hh];
#pragma unroll
    for (int m = 1; m < 64; m <<= 1) {
#pragma unroll
        for (int hh = 0; hh < 4; hh++) pb[hh] += __shfl_xor(pb[hh], m);
    }
    if (lane == 0) {
        int q = row >> 8, k = row & 255;
#pragma unroll
        for (int hh = 0; hh < 4; hh++)
            bias2[hh * NN + k * 256 + q] = pb[hh] * 1.4426950408889634f;
    }
}

// ---------------- fused QKVG projection GEMM (z staged once per block) ----------------
// q,k,v written head-major [h][row][32]; g written [row][128]
__global__ __launch_bounds__(256) void proj_kernel(const bf16_t* __restrict__ z,
                                                   const bf16_t* __restrict__ wt,
                                                   bf16_t* __restrict__ outbase) {
    __shared__ bf16_t As[64][136];
    __shared__ bf16_t Bs[64][136];
    int t = threadIdx.x;
    int rb = blockIdx.x;
#pragma unroll
    for (int i = 0; i < 4; i++) {
        int c = i * 256 + t;
        int r = c >> 4, off = (c & 15) * 8;
        *reinterpret_cast<bf16x8*>(&As[r][off]) =
            *reinterpret_cast<const bf16x8*>(&z[(rb * 64 + r) * 128 + off]);
    }
    __syncthreads();
    int w = t >> 6, lane = t & 63;
    int lx = lane & 15, ly = lane >> 4;
    int m0 = (w >> 1) * 32, n0 = (w & 1) * 32;
    bf16x8 af[2][4];
#pragma unroll
    for (int mt = 0; mt < 2; mt++)
#pragma unroll
        for (int ks = 0; ks < 4; ks++)
            af[mt][ks] = *reinterpret_cast<bf16x8*>(&As[m0 + mt * 16 + lx][ks * 32 + ly * 8]);

    for (int nb = 0; nb < 8; nb++) {
        int mat = nb >> 1, nc0 = (nb & 1) * 64;
        const bf16_t* wm = wt + mat * 16384;
#pragma unroll
        for (int i = 0; i < 4; i++) {
            int c = i * 256 + t;
            int r = c >> 4, off = (c & 15) * 8;
            *reinterpret_cast<bf16x8*>(&Bs[r][off]) =
                *reinterpret_cast<const bf16x8*>(&wm[(nc0 + r) * 128 + off]);
        }
        __syncthreads();
        f32x4 acc[2][2];
#pragma unroll
        for (int mt = 0; mt < 2; mt++)
#pragma unroll
            for (int nt = 0; nt < 2; nt++) acc[mt][nt] = (f32x4){0.f, 0.f, 0.f, 0.f};
#pragma unroll
        for (int ks = 0; ks < 4; ks++) {
            bf16x8 bfr[2];
#pragma unroll
            for (int nt = 0; nt < 2; nt++)
                bfr[nt] = *reinterpret_cast<bf16x8*>(&Bs[n0 + nt * 16 + lx][ks * 32 + ly * 8]);
#pragma unroll
            for (int mt = 0; mt < 2; mt++)
#pragma unroll
                for (int nt = 0; nt < 2; nt++)
                    acc[mt][nt] = __builtin_amdgcn_mfma_f32_16x16x32_bf16(af[mt][ks], bfr[nt], acc[mt][nt], 0, 0, 0);
        }
        bf16_t* dst = outbase + (size_t)mat * ((size_t)NN * 128);
#pragma unroll
        for (int mt = 0; mt < 2; mt++)
#pragma unroll
            for (int nt = 0; nt < 2; nt++)
#pragma unroll
                for (int r = 0; r < 4; r++) {
                    int row = rb * 64 + m0 + mt * 16 + ly * 4 + r;
                    int col = nc0 + n0 + nt * 16 + lx;
                    float v = acc[mt][nt][r];
                    if (mat == 3) {
                        v = 1.0f / (1.0f + __expf(-v));  // fused sigmoid for G
                        dst[row * 128 + col] = (bf16_t)v;
                    } else {
                        // head-major: [h][row][32]
                        dst[((size_t)(col >> 5) * NN + row) * 32 + (col & 31)] = (bf16_t)v;
                    }
                }
        __syncthreads();
    }
}

// ---------------- attention: swapped QK^T, online in-register softmax ----------------
// q/k/v/om head-major [h][row][32]; bias2 [h][key][q]
__global__ __launch_bounds__(256, 4) void attn_kernel(const bf16_t* __restrict__ qh,
                                                      const bf16_t* __restrict__ kh,
                                                      const bf16_t* __restrict__ vh,
                                                      const float* __restrict__ bias2,
                                                      bf16_t* __restrict__ om2) {
    __shared__ bf16_t Kl[256][44];   // 88B rows -> 2-way (free)
    __shared__ bf16_t Vt[32][268];   // 536B rows -> 2-way (free)
    int t = threadIdx.x;
    int b = blockIdx.x >> 2, h = blockIdx.x & 3;
    const bf16_t* kbase = kh + ((size_t)h * NN + b * 256) * 32;
    const bf16_t* vbase = vh + ((size_t)h * NN + b * 256) * 32;
    // stage K (coalesced 16KB contiguous)
#pragma unroll
    for (int i = 0; i < 4; i++) {
        int c = i * 256 + t;
        int key = c >> 2, slot = c & 3;
        *reinterpret_cast<bf16x8*>(&Kl[key][slot * 8]) =
            *reinterpret_cast<const bf16x8*>(&kbase[key * 32 + slot * 8]);
    }
    // stage V transposed
    {
        bf16x8 vv[4];
#pragma unroll
        for (int j = 0; j < 4; j++)
            vv[j] = *reinterpret_cast<const bf16x8*>(&vbase[t * 32 + j * 8]);
#pragma unroll
        for (int j = 0; j < 4; j++)
#pragma unroll
            for (int e = 0; e < 8; e++) Vt[j * 8 + e][t] = vv[j][e];
    }
    __syncthreads();

    int w = t >> 6, lane = t & 63;
    int rsel = lane & 31, hi = lane >> 5;
    int hi8 = hi * 8;
    bool lo = (hi == 0);
    const float SCL2 = 0.17677669529663687f * 1.4426950408889634f;  // scale * log2(e)

    for (int qt = 0; qt < 2; qt++) {
        int qpos = w * 64 + qt * 32 + rsel;
        const bf16_t* qrow = qh + ((size_t)h * NN + b * 256 + qpos) * 32;
        bf16x8 qf0 = *reinterpret_cast<const bf16x8*>(qrow + hi8);
        bf16x8 qf1 = *reinterpret_cast<const bf16x8*>(qrow + 16 + hi8);
        const float* bq = bias2 + (size_t)h * NN + qpos;  // + key*256

        f32x16 of;
#pragma unroll
        for (int i = 0; i < 16; i++) of[i] = 0.f;
        float m = -1e30f, l = 0.f;

        for (int kt = 0; kt < 8; kt++) {
            bf16x8 k0 = *reinterpret_cast<bf16x8*>(&Kl[kt * 32 + rsel][hi8]);
            bf16x8 k1 = *reinterpret_cast<bf16x8*>(&Kl[kt * 32 + rsel][16 + hi8]);
            f32x16 s;
#pragma unroll
            for (int i = 0; i < 16; i++) s[i] = 0.f;
            s = __builtin_amdgcn_mfma_f32_32x32x16_bf16(k0, qf0, s, 0, 0, 0);
            s = __builtin_amdgcn_mfma_f32_32x32x16_bf16(k1, qf1, s, 0, 0, 0);
            // bias gather: coalesced across lanes (consecutive q)
            float bv[16];
#pragma unroll
            for (int e = 0; e < 16; e++) {
                int key = kt * 32 + 8 * (e >> 2) + 4 * hi + (e & 3);
                bv[e] = bq[(size_t)key * 256];
            }
            float pm = -1e30f;
#pragma unroll
            for (int e = 0; e < 16; e++) {
                float v = s[e] * SCL2 + bv[e];
                s[e] = v;
                pm = fmaxf(pm, v);
            }
            pm = fmaxf(pm, __shfl_xor(pm, 32));
            float nm = fmaxf(m, pm);
            float al = __builtin_amdgcn_exp2f(m - nm);
            m = nm;
            float cs = 0.f;
#pragma unroll
            for (int e = 0; e < 16; e++) {
                float p = __builtin_amdgcn_exp2f(s[e] - m);
                s[e] = p;
                cs += p;
            }
            l = l * al + cs;
#pragma unroll
            for (int i = 0; i < 16; i++) of[i] *= al;
            // build P^T B-fragments
            u32 wv[8];
#pragma unroll
            for (int g = 0; g < 4; g++) {
                wv[2 * g] = pk2(s[4 * g], s[4 * g + 1]);
                wv[2 * g + 1] = pk2(s[4 * g + 2], s[4 * g + 3]);
            }
            u32 p0 = __shfl_xor(wv[0], 32), p1 = __shfl_xor(wv[1], 32);
            u32 p2 = __shfl_xor(wv[2], 32), p3 = __shfl_xor(wv[3], 32);
            u32 p4 = __shfl_xor(wv[4], 32), p5 = __shfl_xor(wv[5], 32);
            u32 p6 = __shfl_xor(wv[6], 32), p7 = __shfl_xor(wv[7], 32);
            bf16x8 pf0 = frag4(lo ? wv[0] : p2, lo ? wv[1] : p3,
                               lo ? p0 : wv[2], lo ? p1 : wv[3]);
            bf16x8 pf1 = frag4(lo ? wv[4] : p6, lo ? wv[5] : p7,
                               lo ? p4 : wv[6], lo ? p5 : wv[7]);
            // PV
            bf16x8 va = *reinterpret_cast<bf16x8*>(&Vt[rsel][kt * 32 + hi8]);
            bf16x8 vb = *reinterpret_cast<bf16x8*>(&Vt[rsel][kt * 32 + 16 + hi8]);
            of = __builtin_amdgcn_mfma_f32_32x32x16_bf16(va, pf0, of, 0, 0, 0);
            of = __builtin_amdgcn_mfma_f32_32x32x16_bf16(vb, pf1, of, 0, 0, 0);
        }

        l += __shfl_xor(l, 32);
        float linv = 1.0f / l;
        u32 ow[8];
#pragma unroll
        for (int g = 0; g < 4; g++) {
            ow[2 * g] = pk2(of[4 * g] * linv, of[4 * g + 1] * linv);
            ow[2 * g + 1] = pk2(of[4 * g + 2] * linv, of[4 * g + 3] * linv);
        }
        u32 q0 = __shfl_xor(ow[0], 32), q1 = __shfl_xor(ow[1], 32);
        u32 q2 = __shfl_xor(ow[2], 32), q3 = __shfl_xor(ow[3], 32);
        u32 q4 = __shfl_xor(ow[4], 32), q5 = __shfl_xor(ow[5], 32);
        u32 q6 = __shfl_xor(ow[6], 32), q7 = __shfl_xor(ow[7], 32);
        u32x4 st0 = {lo ? ow[0] : q2, lo ? ow[1] : q3, lo ? q0 : ow[2], lo ? q1 : ow[3]};
        u32x4 st1 = {lo ? ow[4] : q6, lo ? ow[5] : q7, lo ? q4 : ow[6], lo ? q5 : ow[7]};
        bf16_t* orow = om2 + ((size_t)h * NN + b * 256 + qpos) * 32;
        *reinterpret_cast<u32x4*>(orow + hi8) = st0;
        *reinterpret_cast<u32x4*>(orow + 16 + hi8) = st1;
    }
}

// ---------------- final: out = (o*g) @ Wo, fp32 out ----------------
__global__ __launch_bounds__(256) void final_kernel(const bf16_t* __restrict__ om2,
                                                    const bf16_t* __restrict__ gm,
                                                    const bf16_t* __restrict__ wot,
                                                    float* __restrict__ out) {
    __shared__ bf16_t As[64][136];
    __shared__ bf16_t Bs[64][136];
    int t = threadIdx.x;
    int rb = blockIdx.x;
#pragma unroll
    for (int i = 0; i < 4; i++) {
        int c = i * 256 + t;
        int r = c >> 4, off = (c & 15) * 8;
        bf16x8 o8 = *reinterpret_cast<const bf16x8*>(
            &om2[((size_t)(off >> 5) * NN + rb * 64 + r) * 32 + (off & 31)]);
        bf16x8 g8 = *reinterpret_cast<const bf16x8*>(&gm[(rb * 64 + r) * 128 + off]);
        bf16x8 p8;
#pragma unroll
        for (int e = 0; e < 8; e++) p8[e] = (bf16_t)((float)o8[e] * (float)g8[e]);
        *reinterpret_cast<bf16x8*>(&As[r][off]) = p8;
    }
    __syncthreads();
    int w = t >> 6, lane = t & 63;
    int lx = lane & 15, ly = lane >> 4;
    int m0 = (w >> 1) * 32, n0 = (w & 1) * 32;
    bf16x8 af[2][4];
#pragma unroll
    for (int mt = 0; mt < 2; mt++)
#pragma unroll
        for (int ks = 0; ks < 4; ks++)
            af[mt][ks] = *reinterpret_cast<bf16x8*>(&As[m0 + mt * 16 + lx][ks * 32 + ly * 8]);

    for (int half = 0; half < 2; half++) {
        int nc0 = half * 64;
#pragma unroll
        for (int i = 0; i < 4; i++) {
            int c = i * 256 + t;
            int r = c >> 4, off = (c & 15) * 8;
            *reinterpret_cast<bf16x8*>(&Bs[r][off]) =
                *reinterpret_cast<const bf16x8*>(&wot[(nc0 + r) * 128 + off]);
        }
        __syncthreads();
        f32x4 acc[2][2];
#pragma unroll
        for (int mt = 0; mt < 2; mt++)
#pragma unroll
            for (int nt = 0; nt < 2; nt++) acc[mt][nt] = (f32x4){0.f, 0.f, 0.f, 0.f};
#pragma unroll
        for (int ks = 0; ks < 4; ks++) {
            bf16x8 bfr[2];
#pragma unroll
            for (int nt = 0; nt < 2; nt++)
                bfr[nt] = *reinterpret_cast<bf16x8*>(&Bs[n0 + nt * 16 + lx][ks * 32 + ly * 8]);
#pragma unroll
            for (int mt = 0; mt < 2; mt++)
#pragma unroll
                for (int nt = 0; nt < 2; nt++)
                    acc[mt][nt] = __builtin_amdgcn_mfma_f32_16x16x32_bf16(af[mt][ks], bfr[nt], acc[mt][nt], 0, 0, 0);
        }
#pragma unroll
        for (int mt = 0; mt < 2; mt++)
#pragma unroll
            for (int nt = 0; nt < 2; nt++)
#pragma unroll
                for (int r = 0; r < 4; r++) {
                    int row = rb * 64 + m0 + mt * 16 + ly * 4 + r;
                    int col = nc0 + n0 + nt * 16 + lx;
                    out[row * 128 + col] = acc[mt][nt][r];
                }
        __syncthreads();
    }
}

extern "C" void kernel_launch(void* const* d_in, const int* in_sizes, int n_in,
                              void* d_out, int out_size, void* d_ws, size_t ws_size,
                              hipStream_t stream) {
    const float* x   = (const float*)d_in[0];
    const float* lnw = (const float*)d_in[1];
    const float* lnb = (const float*)d_in[2];
    const float* Wb  = (const float*)d_in[3];
    const float* Wq  = (const float*)d_in[4];
    const float* Wk  = (const float*)d_in[5];
    const float* Wv  = (const float*)d_in[6];
    const float* Wg  = (const float*)d_in[7];
    const float* Wo  = (const float*)d_in[8];
    float* out = (float*)d_out;

    char* ws = (char*)d_ws;
    const size_t MAT = (size_t)NN * 128 * sizeof(bf16_t);  // 16 MB
    bf16_t* z     = (bf16_t*)(ws);
    bf16_t* qkvg  = (bf16_t*)(ws + MAT);          // q,k,v (head-major), g contiguous
    bf16_t* omat  = (bf16_t*)(ws + 5 * MAT);
    bf16_t* wt    = (bf16_t*)(ws + 6 * MAT);      // 5 * 128*128 bf16
    float*  bias2 = (float*)(ws + 6 * MAT + 163840);

    bf16_t* q = qkvg;
    bf16_t* k = qkvg + (size_t)NN * 128;
    bf16_t* v = qkvg + 2 * (size_t)NN * 128;
    bf16_t* g = qkvg + 3 * (size_t)NN * 128;

    convw_kernel<<<640, 128, 0, stream>>>(Wq, Wk, Wv, Wg, Wo, wt);
    ln_kernel<<<16384, 256, 0, stream>>>(x, lnw, lnb, Wb, z, bias2);
    proj_kernel<<<1024, 256, 0, stream>>>(z, wt, qkvg);
    attn_kernel<<<1024, 256, 0, stream>>>(q, k, v, bias2, omat);
    final_kernel<<<1024, 256, 0, stream>>>(omat, g, wt + 4 * 16384, out);
}